// Round 8
// baseline (76.281 us; speedup 1.0000x reference)
//
#include <hip/hip_runtime.h>
#include <hip/hip_bf16.h>

// Head attention: x[4,4096,1024] f32, Wq/Wk/Wv[1024,64] f32 -> out[4,4096,64] f32
// v8 = v7 with one fix: inline-asm v_exp_f32 -> exp2f().
//   (TRANS-op wait-state hazard: the hazard recognizer can't see inside
//    INLINEASM, so consumers read v_exp's VDST before it retires -> garbage.
//    exp2f lowers to v_exp_f32 WITH compiler-managed hazards.)
//   attnQ: 8 waves = 2 qgroups(32 rows) x 4 KV-quarters; KV sub-tile 32;
//          exp2 direct (log2e folded into Wq); sequential-barrier merge.

#define BB 4
#define TT 4096
#define CC 1024
#define HH 64

typedef __attribute__((ext_vector_type(8))) short bf16x8;
typedef __attribute__((ext_vector_type(4))) float f32x4;

__device__ __forceinline__ short f2bf(float f) {
  union { float f; unsigned u; } v; v.f = f;
  unsigned r = v.u + 0x7fffu + ((v.u >> 16) & 1u);  // RNE
  return (short)(r >> 16);
}

// ---------------- wtf: W -> WtF[nf 12][ks 32][lane 64][8] bf16 ---------------
// q part scaled by C^-0.5 * log2(e)  (so softmax exp == exp2 of logits)
__global__ void wtf_kernel(const float* __restrict__ Wq, const float* __restrict__ Wk,
                           const float* __restrict__ Wv, short* __restrict__ WtF) {
  int idx = blockIdx.x * 256 + threadIdx.x;       // 12*32*64 = 24576
  int lane = idx & 63, ks = (idx >> 6) & 31, nf = idx >> 11;
  int l15 = lane & 15, lg = lane >> 4;
  int n = nf * 16 + l15;
  const float* W = (n < HH) ? Wq : ((n < 2 * HH) ? Wk : Wv);
  float sc = (n < HH) ? (0.03125f * 1.44269504f) : 1.0f;
  int k0 = ks * 32 + lg * 8, h = n & (HH - 1);
  bf16x8 r;
#pragma unroll
  for (int j = 0; j < 8; ++j) r[j] = f2bf(W[(k0 + j) * HH + h] * sc);
  *(bf16x8*)(WtF + (size_t)idx * 8) = r;
}

// ---------------- proj: fused staging + nf-split MFMA ------------------------
__launch_bounds__(256, 4)
__global__ void proj_kernel(const float* __restrict__ x, const short* __restrict__ WtF,
                            short* __restrict__ qo, short* __restrict__ ko,
                            short* __restrict__ vTo) {
  __shared__ __align__(16) short xs[16 * 1024];   // 32 KB
  int t = threadIdx.x;
  int row0 = blockIdx.x * 16;

  {  // ---- stage x[16][1024] f32 -> bf16 frag-order LDS, XOR-swizzled ----
    int r = t >> 4, kc = t & 15;
    const float4* xr4 = (const float4*)(x + (size_t)(row0 + r) * CC) + kc * 2;
#pragma unroll
    for (int i = 0; i < 8; ++i) {
      float4 a = xr4[i * 32], b2 = xr4[i * 32 + 1];
      bf16x8 w;
      w[0] = f2bf(a.x);  w[1] = f2bf(a.y);  w[2] = f2bf(a.z);  w[3] = f2bf(a.w);
      w[4] = f2bf(b2.x); w[5] = f2bf(b2.y); w[6] = f2bf(b2.z); w[7] = f2bf(b2.w);
      int c = kc + i * 16;
      int S = (c * 256 + r * 16) ^ ((c & 7) << 4);
      *(bf16x8*)((char*)xs + S) = w;
    }
  }
  __syncthreads();

  int wave = t >> 6, lane = t & 63;
  int l15 = lane & 15, lg = lane >> 4;
  int nf0 = wave * 3;
  const short* wp = WtF + ((size_t)nf0 * 32 * 64 + (size_t)lane) * 8;
  const char* xsb = (const char*)xs;

  f32x4 acc[3];
#pragma unroll
  for (int j = 0; j < 3; ++j) acc[j] = (f32x4){0.f, 0.f, 0.f, 0.f};

  bf16x8 wA[3], wB[3];
#pragma unroll
  for (int j = 0; j < 3; ++j) wA[j] = *(const bf16x8*)(wp + (size_t)j * 32 * 512);

#pragma unroll
  for (int ks = 0; ks < 32; ks += 2) {
#pragma unroll
    for (int j = 0; j < 3; ++j)
      wB[j] = *(const bf16x8*)(wp + ((size_t)j * 32 + ks + 1) * 512);
    bf16x8 a0 = *(const bf16x8*)(xsb + ks * 1024 +
                   ((lane * 16) ^ ((((ks * 4) + lg) & 7) << 4)));
#pragma unroll
    for (int j = 0; j < 3; ++j)
      acc[j] = __builtin_amdgcn_mfma_f32_16x16x32_bf16(a0, wA[j], acc[j], 0, 0, 0);
    if (ks + 2 < 32) {
#pragma unroll
      for (int j = 0; j < 3; ++j)
        wA[j] = *(const bf16x8*)(wp + ((size_t)j * 32 + ks + 2) * 512);
    }
    bf16x8 a1 = *(const bf16x8*)(xsb + (ks + 1) * 1024 +
                   ((lane * 16) ^ (((((ks + 1) * 4) + lg) & 7) << 4)));
#pragma unroll
    for (int j = 0; j < 3; ++j)
      acc[j] = __builtin_amdgcn_mfma_f32_16x16x32_bf16(a1, wB[j], acc[j], 0, 0, 0);
  }

#pragma unroll
  for (int j = 0; j < 3; ++j) {
    int nf = nf0 + j;
    int h = (nf & 3) * 16 + l15;
    if (nf < 8) {
      short* dst = (nf < 4) ? qo : ko;
#pragma unroll
      for (int reg = 0; reg < 4; ++reg)
        dst[(size_t)(row0 + lg * 4 + reg) * HH + h] = f2bf(acc[j][reg]);
    } else {
      int b = row0 >> 12;
      int trow = (row0 & 4095) + lg * 4;
      short4 s4;
      s4.x = f2bf(acc[j][0]); s4.y = f2bf(acc[j][1]);
      s4.z = f2bf(acc[j][2]); s4.w = f2bf(acc[j][3]);
      *(short4*)(vTo + ((size_t)b * HH + h) * TT + trow) = s4;
    }
  }
}

// ---------------- kperm: k -> kF[b][kt 64][ld 8][lane 64][8] -----------------
__global__ void kperm_kernel(const short* __restrict__ k, short* __restrict__ kF) {
  int idx = blockIdx.x * 256 + threadIdx.x;   // 131072
  int lane = idx & 63, ld = (idx >> 6) & 7, kt = (idx >> 9) & 63, b = idx >> 15;
  int l15 = lane & 15, lg = lane >> 4;
  int kpos = kt * 64 + (ld >> 1) * 16 + l15;
  int e0 = (ld & 1) * 32 + lg * 8;
  bf16x8 r = *(const bf16x8*)(k + ((size_t)b * TT + kpos) * HH + e0);
  *(bf16x8*)(kF + (size_t)idx * 8) = r;
}

// ---------------- vperm: vT -> vF[b][kt 64][ld 8][lane 64][8] ----------------
__global__ void vperm_kernel(const short* __restrict__ vT, short* __restrict__ vF) {
  int idx = blockIdx.x * 256 + threadIdx.x;   // 131072
  int lane = idx & 63, ld = (idx >> 6) & 7, kt = (idx >> 9) & 63, b = idx >> 15;
  int l15 = lane & 15, lg = lane >> 4;
  int h = (ld >> 1) * 16 + l15;
  int spos = kt * 64 + (ld & 1) * 32 + lg * 8;
  bf16x8 r = *(const bf16x8*)(vT + ((size_t)b * HH + h) * TT + spos);
  *(bf16x8*)(vF + (size_t)idx * 8) = r;
}

// ---------------- attnQ: 32 q-rows/wave, 4-quarter KV split ------------------
// grid 256 x 512 thr. wave = (qg 0..1) x (qr 0..3): 32 q-rows, 1024 KV slice.
// KV sub-tile = 32 positions: 4 K-slice + 4 V-slice contiguous 1KB loads/iter.
// Fixed-max softmax via exp2f (log2e pre-folded into Wq). P roundtrip in
// wave-private swizzled LDS (rows 80B). Merge: sequential-barrier LDS add.
__launch_bounds__(512, 2)
__global__ void attnQ_kernel(const short* __restrict__ q, const short* __restrict__ kF,
                             const short* __restrict__ vF, float* __restrict__ out) {
  __shared__ __align__(16) short ps[8][1280];     // 20 KB: 2 P-tiles/wave, 80B rows
  __shared__ __align__(16) float macc[64][68];    // 17.4 KB merge O
  __shared__ float lL[64];
  int wave = threadIdx.x >> 6, lane = threadIdx.x & 63;
  int l15 = lane & 15, lg = lane >> 4;
  int qg = wave & 1, qr = wave >> 1;
  int low3 = blockIdx.x & 7;                 // XCD id (perf heuristic only)
  int b  = low3 >> 1;                        // 2 XCDs per batch -> L2-resident KV
  int qt = ((blockIdx.x >> 3) << 1) | (low3 & 1);   // 0..63
  int brow0 = qt * 64;
  int rowW = brow0 + qg * 32;

  const short* qb = q + ((size_t)b * TT + rowW + l15) * HH;
  bf16x8 qa[2][2];
  qa[0][0] = *(const bf16x8*)(qb + lg * 8);
  qa[0][1] = *(const bf16x8*)(qb + 32 + lg * 8);
  qa[1][0] = *(const bf16x8*)(qb + 16 * HH + lg * 8);
  qa[1][1] = *(const bf16x8*)(qb + 16 * HH + 32 + lg * 8);

  const short* kfb = kF + (size_t)b * (64 * 8 * 64 * 8) + (size_t)lane * 8;
  const short* vfb = vF + (size_t)b * (64 * 8 * 64 * 8) + (size_t)lane * 8;

  f32x4 acc[2][4];
#pragma unroll
  for (int g = 0; g < 2; ++g)
#pragma unroll
    for (int i = 0; i < 4; ++i) acc[g][i] = (f32x4){0.f, 0.f, 0.f, 0.f};
  float lsum[2][4] = {{0.f, 0.f, 0.f, 0.f}, {0.f, 0.f, 0.f, 0.f}};

  // P layout (per 16x32 tile): byte(row, kv) = row*80 + ((kv*2) ^ ((row>>3)<<4))
  char* psw = (char*)&ps[wave][0];
  int pw = lg * 4 * 80 + ((l15 * 2) ^ ((lg >> 1) << 4));  // + reg*80 + cf*32 + g*1280
  int pr = l15 * 80 + ((lg ^ (l15 >> 3)) << 4);           // + g*1280

  for (int t = qr * 32; t < qr * 32 + 32; ++t) {
    const short* kp = kfb + (size_t)t * 2048;
    const short* vp = vfb + (size_t)(t >> 1) * 4096 + (size_t)(t & 1) * 512;
    bf16x8 kf[4], vf[4];
#pragma unroll
    for (int ld = 0; ld < 4; ++ld) kf[ld] = *(const bf16x8*)(kp + ld * 512);
#pragma unroll
    for (int hf = 0; hf < 4; ++hf) vf[hf] = *(const bf16x8*)(vp + hf * 1024);
    // ---- S = q k^T (32 rows x 32 kv), p = exp2(s) -> swizzled LDS ----
#pragma unroll
    for (int g = 0; g < 2; ++g)
#pragma unroll
      for (int cf = 0; cf < 2; ++cf) {
        f32x4 t4 = (f32x4){0.f, 0.f, 0.f, 0.f};
        t4 = __builtin_amdgcn_mfma_f32_16x16x32_bf16(qa[g][0], kf[cf * 2], t4, 0, 0, 0);
        t4 = __builtin_amdgcn_mfma_f32_16x16x32_bf16(qa[g][1], kf[cf * 2 + 1], t4, 0, 0, 0);
#pragma unroll
        for (int reg = 0; reg < 4; ++reg) {
          float p = exp2f(t4[reg]);
          lsum[g][reg] += p;
          *(short*)(psw + (g * 1280 + pw + reg * 80 + cf * 32)) = f2bf(p);
        }
      }
    // ---- O += P V (K=32, one MFMA per (g,hf)) ----
    bf16x8 pa0 = *(const bf16x8*)(psw + pr);
    bf16x8 pa1 = *(const bf16x8*)(psw + 1280 + pr);
    __builtin_amdgcn_s_setprio(1);
#pragma unroll
    for (int hf = 0; hf < 4; ++hf) {
      acc[0][hf] = __builtin_amdgcn_mfma_f32_16x16x32_bf16(pa0, vf[hf], acc[0][hf], 0, 0, 0);
      acc[1][hf] = __builtin_amdgcn_mfma_f32_16x16x32_bf16(pa1, vf[hf], acc[1][hf], 0, 0, 0);
    }
    __builtin_amdgcn_s_setprio(0);
  }

  // ---- deferred l reduce (16-lane column groups) ----
#pragma unroll
  for (int g = 0; g < 2; ++g)
#pragma unroll
    for (int reg = 0; reg < 4; ++reg) {
      float r = lsum[g][reg];
      r += __shfl_xor(r, 1); r += __shfl_xor(r, 2);
      r += __shfl_xor(r, 4); r += __shfl_xor(r, 8);
      lsum[g][reg] = r;
    }

  // ---- merge 4 quarters: sequential-barrier LDS accumulation ----
#pragma unroll
  for (int ph = 0; ph < 4; ++ph) {
    if (qr == ph) {
#pragma unroll
      for (int g = 0; g < 2; ++g) {
#pragma unroll
        for (int reg = 0; reg < 4; ++reg) {
          int row = qg * 32 + g * 16 + lg * 4 + reg;
          if (ph == 0) {
#pragma unroll
            for (int hf = 0; hf < 4; ++hf)
              macc[row][hf * 16 + l15] = acc[g][hf][reg];
            if (l15 == 0) lL[row] = lsum[g][reg];
          } else {
#pragma unroll
            for (int hf = 0; hf < 4; ++hf)
              macc[row][hf * 16 + l15] += acc[g][hf][reg];
            if (l15 == 0) lL[row] += lsum[g][reg];
          }
        }
      }
    }
    __syncthreads();
  }

  // ---- normalize + store ----
  {
    int t = threadIdx.x;
    int r = t >> 3, c0 = (t & 7) * 8;
    float linv = 1.0f / lL[r];
    float4 o0, o1;
    o0.x = macc[r][c0 + 0] * linv; o0.y = macc[r][c0 + 1] * linv;
    o0.z = macc[r][c0 + 2] * linv; o0.w = macc[r][c0 + 3] * linv;
    o1.x = macc[r][c0 + 4] * linv; o1.y = macc[r][c0 + 5] * linv;
    o1.z = macc[r][c0 + 6] * linv; o1.w = macc[r][c0 + 7] * linv;
    float* op = out + ((size_t)b * TT + brow0 + r) * HH + c0;
    *(float4*)op = o0;
    *(float4*)(op + 4) = o1;
  }
}

extern "C" void kernel_launch(void* const* d_in, const int* in_sizes, int n_in,
                              void* d_out, int out_size, void* d_ws, size_t ws_size,
                              hipStream_t stream) {
  const float* x  = (const float*)d_in[0];
  const float* Wq = (const float*)d_in[1];
  const float* Wk = (const float*)d_in[2];
  const float* Wv = (const float*)d_in[3];
  float* out = (float*)d_out;

  char* ws = (char*)d_ws;
  short* WtF = (short*)ws;                 // 384 KB (pad to 512K)
  short* q   = (short*)(ws + 0x080000);    // 2 MB
  short* k   = (short*)(ws + 0x280000);    // 2 MB
  short* vT  = (short*)(ws + 0x480000);    // 2 MB
  short* kF  = (short*)(ws + 0x680000);    // 2 MB
  short* vF  = (short*)(ws + 0x880000);    // 2 MB -> 10.5 MB total

  hipLaunchKernelGGL(wtf_kernel,   dim3(96),   dim3(256), 0, stream, Wq, Wk, Wv, WtF);
  hipLaunchKernelGGL(proj_kernel,  dim3(1024), dim3(256), 0, stream, x, WtF, q, k, vT);
  hipLaunchKernelGGL(kperm_kernel, dim3(512),  dim3(256), 0, stream, k, kF);
  hipLaunchKernelGGL(vperm_kernel, dim3(512),  dim3(256), 0, stream, vT, vF);
  hipLaunchKernelGGL(attnQ_kernel, dim3(256),  dim3(512), 0, stream, q, kF, vF, out);
}